// Round 4
// baseline (91.266 us; speedup 1.0000x reference)
//
#include <hip/hip_runtime.h>
#include <math.h>

#define BATCH   1024
#define NQ      10
#define DIM     1024      // 2^NQ
#define HID     10
#define DEPTH   3
#define WINDOW  64
#define NFREQ   33
#define FFT_DIM 66
#define PI_F       3.14159265358979323846f
#define INV_SQRT2  0.70710678118654752440f

// ---------------------------------------------------------------------------
// Kernel 1: per-batch feature pipeline:
//   rfft(x[64]) -> mag=log1p(|F|), phs=angle/pi -> feat[66]
//   x_proj = tanh(feat @ Wi.T + bi)*pi ; h_proj = tanh([c_mag,c_phase] @ Wh.T + bh)*pi
//   comb = x_proj + h_proj   (B x 10)
// One wave (64 threads) per batch element.
// ---------------------------------------------------------------------------
__global__ __launch_bounds__(64) void k_comb(
    const float* __restrict__ x,
    const float* __restrict__ c_mag,
    const float* __restrict__ c_phase,
    const float* __restrict__ Wi,
    const float* __restrict__ bi,
    const float* __restrict__ Wh,
    const float* __restrict__ bh,
    float* __restrict__ comb)
{
    const int b = blockIdx.x;
    const int t = threadIdx.x;

    __shared__ float xs[WINDOW];
    __shared__ float ctab[WINDOW], stab[WINDOW];
    __shared__ float feat[FFT_DIM];
    __shared__ float hin[2 * HID];

    xs[t] = x[b * WINDOW + t];
    {
        float sv, cv;
        sincosf((2.0f * PI_F / 64.0f) * (float)t, &sv, &cv);
        ctab[t] = cv; stab[t] = sv;
    }
    if (t < 2 * HID)
        hin[t] = (t < HID) ? c_mag[b * HID + t] : c_phase[b * HID + (t - HID)];
    __syncthreads();

    if (t < NFREQ) {
        // F[t] = sum_n x[n] * exp(-2*pi*i*t*n/64); twiddle index m=(t*n)&63
        float re = 0.f, im = 0.f;
        int m = 0;
        for (int n = 0; n < WINDOW; ++n) {
            float xv = xs[n];
            re += xv * ctab[m];
            im -= xv * stab[m];
            m = (m + t) & 63;
        }
        // DC (t=0) and Nyquist (t=32) bins are structurally real; the table
        // has stab[32] = sinf(pi) ~ -8.7e-8 != 0, which makes sign(im) random
        // and flips atan2 between +pi/-pi when re<0. Pin im = +0 so
        // angle = +pi exactly like the reference FFT.
        if (t == 0 || t == 32) im = 0.0f;
        feat[t]         = log1pf(sqrtf(re * re + im * im));
        feat[NFREQ + t] = atan2f(im, re) * (1.0f / PI_F);
    }
    __syncthreads();

    if (t < NQ) {
        float acc = bi[t];
        const float* wrow = Wi + t * FFT_DIM;
        for (int j = 0; j < FFT_DIM; ++j) acc += feat[j] * wrow[j];
        float xp = tanhf(acc) * PI_F;

        float acc2 = bh[t];
        const float* hrow = Wh + t * (2 * HID);
        for (int j = 0; j < 2 * HID; ++j) acc2 += hin[j] * hrow[j];
        float hp = tanhf(acc2) * PI_F;

        comb[b * NQ + t] = xp + hp;
    }
}

// ---------------------------------------------------------------------------
// Kernel 2: VQC statevector sim. grid = BATCH*4 (4 LSTM gates), 256 threads.
// State (1024 complex f32, 8KB) lives in LDS.
//   encoding: per qubit i fused M = RX(fs*c) * RY(c) * H   (10 passes)
//   per layer: entangler = Gray-code permutation new[j]=old[j^(j>>1)] (1 pass)
//              + 10 RY(var) passes
//   measure: <Z_i> for i=0..9 -> gates[g][b][i]
// Qubit i acts on bit (9-i)  (stride 2^(9-i)).
// ---------------------------------------------------------------------------
__global__ __launch_bounds__(256) void k_vqc(
    const float* __restrict__ comb,
    const float* __restrict__ fs0, const float* __restrict__ vp0,
    const float* __restrict__ fs1, const float* __restrict__ vp1,
    const float* __restrict__ fs2, const float* __restrict__ vp2,
    const float* __restrict__ fs3, const float* __restrict__ vp3,
    float* __restrict__ gates)
{
    const int blk = blockIdx.x;
    const int b = blk >> 2;
    const int g = blk & 3;
    const float* fs = (g == 0) ? fs0 : (g == 1) ? fs1 : (g == 2) ? fs2 : fs3;
    const float* vp = (g == 0) ? vp0 : (g == 1) ? vp1 : (g == 2) ? vp2 : vp3;
    const int t = threadIdx.x;

    __shared__ float2 st[DIM];
    __shared__ float gc[2 * NQ + DEPTH * NQ];   // cos(angle/2)
    __shared__ float gs[2 * NQ + DEPTH * NQ];   // sin(angle/2)
    __shared__ float part[4 * NQ];

    // --- precompute all gate (cos,sin) params: 10 RY-enc, 10 RX-enc, 30 RY-var
    if (t < 2 * NQ + DEPTH * NQ) {
        float ang;
        if (t < NQ)            ang = 0.5f * comb[b * NQ + t];
        else if (t < 2 * NQ) { int q = t - NQ; ang = 0.5f * fs[q] * comb[b * NQ + q]; }
        else                   ang = 0.5f * vp[t - 2 * NQ];
        float s_, c_;
        sincosf(ang, &s_, &c_);
        gc[t] = c_; gs[t] = s_;
    }
    // --- init |0...0>
    for (int k = t; k < DIM; k += 256)
        st[k] = make_float2(k == 0 ? 1.f : 0.f, 0.f);
    __syncthreads();

    // --- encoding: fused complex 2x2 per qubit:  M = RX * RY * H
    for (int i = 0; i < NQ; ++i) {
        const int s = 1 << (9 - i);
        const float c1 = gc[i], s1 = gs[i];
        const float c2 = gc[NQ + i], s2 = gs[NQ + i];
        const float ap = c1 - s1, am = c1 + s1;
        const float m00r =  INV_SQRT2 * c2 * ap;
        const float m00i = -INV_SQRT2 * s2 * am;
        const float m01r =  INV_SQRT2 * c2 * am;
        const float m01i =  INV_SQRT2 * s2 * ap;
        const float m10r =  m01r;
        const float m10i = -m01i;
        const float m11r = -m00r;
        const float m11i =  m00i;
        #pragma unroll
        for (int r = 0; r < 2; ++r) {
            const int p  = t + r * 256;
            const int lo = ((p & ~(s - 1)) << 1) | (p & (s - 1));
            const int hi = lo | s;
            float2 a = st[lo], bb = st[hi];
            float2 na, nb;
            na.x = m00r * a.x - m00i * a.y + m01r * bb.x - m01i * bb.y;
            na.y = m00r * a.y + m00i * a.x + m01r * bb.y + m01i * bb.x;
            nb.x = m10r * a.x - m10i * a.y + m11r * bb.x - m11i * bb.y;
            nb.y = m10r * a.y + m10i * a.x + m11r * bb.y + m11i * bb.x;
            st[lo] = na; st[hi] = nb;
        }
        __syncthreads();
    }

    // --- variational layers
    for (int l = 0; l < DEPTH; ++l) {
        // entangler: 9 chained CNOT(i,i+1) == permutation new[j] = old[j ^ (j>>1)]
        float2 v[4];
        #pragma unroll
        for (int r = 0; r < 4; ++r) {
            const int j = t + r * 256;
            v[r] = st[j ^ (j >> 1)];
        }
        __syncthreads();
        #pragma unroll
        for (int r = 0; r < 4; ++r) st[t + r * 256] = v[r];
        __syncthreads();

        for (int i = 0; i < NQ; ++i) {
            const int s = 1 << (9 - i);
            const float c  = gc[2 * NQ + l * NQ + i];
            const float sn = gs[2 * NQ + l * NQ + i];
            #pragma unroll
            for (int r = 0; r < 2; ++r) {
                const int p  = t + r * 256;
                const int lo = ((p & ~(s - 1)) << 1) | (p & (s - 1));
                const int hi = lo | s;
                float2 a = st[lo], bb = st[hi];
                float2 na, nb;
                na.x = c * a.x - sn * bb.x;
                na.y = c * a.y - sn * bb.y;
                nb.x = sn * a.x + c * bb.x;
                nb.y = sn * a.y + c * bb.y;
                st[lo] = na; st[hi] = nb;
            }
            __syncthreads();
        }
    }

    // --- measurement: <Z_i> = sum_k p[k] * (bit(k,9-i) ? -1 : +1)
    float z[NQ];
    #pragma unroll
    for (int i = 0; i < NQ; ++i) z[i] = 0.f;
    #pragma unroll
    for (int r = 0; r < 4; ++r) {
        const int k = t + r * 256;
        float2 a = st[k];
        float p = a.x * a.x + a.y * a.y;
        #pragma unroll
        for (int i = 0; i < NQ; ++i)
            z[i] += (k & (1 << (9 - i))) ? -p : p;
    }
    const int lane = t & 63, wv = t >> 6;
    #pragma unroll
    for (int i = 0; i < NQ; ++i) {
        float vs = z[i];
        for (int off = 32; off > 0; off >>= 1) vs += __shfl_down(vs, off, 64);
        if (lane == 0) part[wv * NQ + i] = vs;
    }
    __syncthreads();
    if (t < NQ) {
        float vs = part[t] + part[NQ + t] + part[2 * NQ + t] + part[3 * NQ + t];
        gates[(g * BATCH + b) * NQ + t] = vs;
    }
}

// ---------------------------------------------------------------------------
// Kernel 3: combine gates, write (out[B], c_mag_new[B*10], c_phase_new[B*10])
// ---------------------------------------------------------------------------
__global__ __launch_bounds__(256) void k_final(
    const float* __restrict__ gates,
    const float* __restrict__ c_mag,
    const float* __restrict__ c_phase,
    const float* __restrict__ Wo,
    const float* __restrict__ bo,
    float* __restrict__ out)
{
    const int b = blockIdx.x * blockDim.x + threadIdx.x;
    if (b >= BATCH) return;
    float acc = bo[0];
    for (int h = 0; h < HID; ++h) {
        const float iv = (gates[(0 * BATCH + b) * HID + h] + 1.f) * 0.5f;
        const float fv = (gates[(1 * BATCH + b) * HID + h] + 1.f) * 0.5f;
        const float gv =  gates[(2 * BATCH + b) * HID + h];
        const float ov = (gates[(3 * BATCH + b) * HID + h] + 1.f) * 0.5f;
        const float cm = c_mag[b * HID + h];
        const float cp = c_phase[b * HID + h];

        const float cmn = fv * cm + iv * fabsf(gv);

        float sg, cg;
        sincosf(gv * PI_F, &sg, &cg);
        const float wrap = atan2f(sg, cg) * (1.0f / PI_F);
        // jnp.remainder(x, 2) = x - 2*floor(x/2), result in [0, 2)
        const float xw = cp + iv * wrap + 1.f;
        float cpn = xw - 2.f * floorf(xw * 0.5f);
        cpn -= 1.f;

        const float ht = ov * cmn * cosf(cpn * PI_F);
        acc += ht * Wo[h];

        out[BATCH + b * HID + h]               = cmn;
        out[BATCH + BATCH * HID + b * HID + h] = cpn;
    }
    out[b] = acc;
}

extern "C" void kernel_launch(void* const* d_in, const int* in_sizes, int n_in,
                              void* d_out, int out_size, void* d_ws, size_t ws_size,
                              hipStream_t stream) {
    const float* x       = (const float*)d_in[0];
    const float* c_mag   = (const float*)d_in[1];
    const float* c_phase = (const float*)d_in[2];
    const float* Wi      = (const float*)d_in[3];
    const float* bi      = (const float*)d_in[4];
    const float* Wh      = (const float*)d_in[5];
    const float* bh      = (const float*)d_in[6];
    const float* fs_i    = (const float*)d_in[7];
    const float* vp_i    = (const float*)d_in[8];
    const float* fs_f    = (const float*)d_in[9];
    const float* vp_f    = (const float*)d_in[10];
    const float* fs_g    = (const float*)d_in[11];
    const float* vp_g    = (const float*)d_in[12];
    const float* fs_o    = (const float*)d_in[13];
    const float* vp_o    = (const float*)d_in[14];
    const float* Wo      = (const float*)d_in[15];
    const float* bo      = (const float*)d_in[16];

    float* out     = (float*)d_out;
    float* comb    = (float*)d_ws;                 // B*NQ floats
    float* gatebuf = comb + BATCH * NQ;            // 4*B*HID floats

    k_comb<<<BATCH, 64, 0, stream>>>(x, c_mag, c_phase, Wi, bi, Wh, bh, comb);
    k_vqc<<<BATCH * 4, 256, 0, stream>>>(comb, fs_i, vp_i, fs_f, vp_f,
                                         fs_g, vp_g, fs_o, vp_o, gatebuf);
    k_final<<<(BATCH + 255) / 256, 256, 0, stream>>>(gatebuf, c_mag, c_phase, Wo, bo, out);
}